// Round 22
// baseline (84.148 us; speedup 1.0000x reference)
//
#include <hip/hip_runtime.h>
#include <hip/hip_bf16.h>

#define NNODES 4096
#define CAP 128
#define STASH 80

// Ledger: R11 grid.sync ~100us. R13 per-node W1 536MB. R15 node-amortize
// stall. R16 head-half XCD (69.4). R17 Ph linearity (64.3). R18 u16 cols +
// folded sinv + ILP2 (59.5). R19/R21 head-quarter XCD, 1-wave attnQ (56.8).
// R20 2-wave -> regression. R22: FEATURE-quarter split -> proj1 slices have
// single owners -> finalize dispatch deleted; scores1 computed on-the-fly in
// attn1 with LDS row stash.

// ---------------------------------------------------------------------------
// Phase 1: blocks [0,1024) = gemm0 tiles (+scores0 +Ph mini-GEMM), issued
// first to overlap under the mask scan; blocks [1024,5120) = edge rows.
// ---------------------------------------------------------------------------
__global__ __launch_bounds__(256) void phase1_kernel(
    const float* __restrict__ mask, int* __restrict__ deg,
    unsigned short* __restrict__ cols, const float* __restrict__ x,
    const float* __restrict__ W0, const float* __restrict__ b0,
    const float* __restrict__ a_src0, const float* __restrict__ a_tgt0,
    const float* __restrict__ W1, float* __restrict__ Ph,
    float* __restrict__ ssrc0, float* __restrict__ stgt0) {
  __shared__ float smem[6144];  // 24 KB
  const int t = threadIdx.x;
  if (blockIdx.x >= 1024) {
    const int n = blockIdx.x - 1024;
    const int lane = t & 63, wid = t >> 6;
    int* wsum = (int*)smem;
    const float4* row = (const float4*)(mask + (size_t)n * NNODES);
    float4 v[4];
    int cnt = 0;
#pragma unroll
    for (int j = 0; j < 4; ++j) {
      v[j] = row[t + 256 * j];  // coalesced
      cnt += (v[j].x == 0.0f) + (v[j].y == 0.0f) + (v[j].z == 0.0f) +
             (v[j].w == 0.0f);
    }
    int xs = cnt;
#pragma unroll
    for (int o = 1; o < 64; o <<= 1) {
      int y = __shfl_up(xs, o);
      if (lane >= o) xs += y;
    }
    if (lane == 63) wsum[wid] = xs;
    __syncthreads();
    int base = 0;
    for (int w = 0; w < wid; ++w) base += wsum[w];
    int off = base + xs - cnt;
    if (t == 0) {
      int total = wsum[0] + wsum[1] + wsum[2] + wsum[3];
      deg[n] = total < CAP ? total : CAP;
    }
    unsigned short* dst = cols + (size_t)n * CAP;
#pragma unroll
    for (int j = 0; j < 4; ++j) {
      const int c0 = (t + 256 * j) * 4;
      float fv[4] = {v[j].x, v[j].y, v[j].z, v[j].w};
#pragma unroll
      for (int k = 0; k < 4; ++k) {
        if (fv[k] == 0.0f) {
          if (off < CAP) dst[off] = (unsigned short)(c0 + k);
          ++off;
        }
      }
    }
  } else {
    // gemm0: 32x64 tile, K=128, BK=32 chunks, 2x4 reg blocking
    float(*As)[36] = (float(*)[36])smem;            // [0,1152)
    float(*Ws)[64] = (float(*)[64])(smem + 1152);   // [1152,3200)
    const int bx = blockIdx.x;
    const int brow = (bx & 127) * 32;
    const int head = bx >> 7;
    const int bcol = head * 64;
    const int tx = t & 15, ty = t >> 4;
    const int ar = t >> 3, ak = (t & 7) * 4;
    float acc[2][4] = {};
    for (int c = 0; c < 4; ++c) {
      const int k0 = c * 32;
      *(float4*)&As[ar][ak] =
          *(const float4*)&x[(size_t)(brow + ar) * 128 + k0 + ak];
#pragma unroll
      for (int q = 0; q < 2; ++q) {
        int i = t + q * 256;
        int k = i >> 4, c4 = (i & 15) * 4;
        *(float4*)&Ws[k][c4] =
            *(const float4*)&W0[(size_t)(k0 + k) * 512 + bcol + c4];
      }
      __syncthreads();
#pragma unroll 2
      for (int kk = 0; kk < 32; kk += 4) {
        float4 a0 = *(const float4*)&As[ty * 2 + 0][kk];
        float4 a1 = *(const float4*)&As[ty * 2 + 1][kk];
#pragma unroll
        for (int j = 0; j < 4; ++j) {
          float4 w = *(const float4*)&Ws[kk + j][tx * 4];
          float av0 = ((const float*)&a0)[j];
          float av1 = ((const float*)&a1)[j];
          acc[0][0] = fmaf(av0, w.x, acc[0][0]);
          acc[0][1] = fmaf(av0, w.y, acc[0][1]);
          acc[0][2] = fmaf(av0, w.z, acc[0][2]);
          acc[0][3] = fmaf(av0, w.w, acc[0][3]);
          acc[1][0] = fmaf(av1, w.x, acc[1][0]);
          acc[1][1] = fmaf(av1, w.y, acc[1][1]);
          acc[1][2] = fmaf(av1, w.z, acc[1][2]);
          acc[1][3] = fmaf(av1, w.w, acc[1][3]);
        }
      }
      __syncthreads();
    }
    // proj0 tile (+bias) -> LDS; fused scores0. Then Ph = tile @ W1slice.
    float(*tile)[64] = (float(*)[64])smem;          // [0,2048)
    float(*W1s)[64] = (float(*)[64])(smem + 2048);  // [2048,6144)
    const float4 bv = *(const float4*)&b0[bcol + tx * 4];
    const float4 as = *(const float4*)&a_src0[head * 64 + tx * 4];
    const float4 at = *(const float4*)&a_tgt0[head * 64 + tx * 4];
#pragma unroll
    for (int r = 0; r < 2; ++r) {
      float4 o;
      o.x = acc[r][0] + bv.x; o.y = acc[r][1] + bv.y;
      o.z = acc[r][2] + bv.z; o.w = acc[r][3] + bv.w;
      const int rowl = ty * 2 + r;
      *(float4*)&tile[rowl][tx * 4] = o;
      float ps = o.x * as.x + o.y * as.y + o.z * as.z + o.w * as.w;
      float pt = o.x * at.x + o.y * at.y + o.z * at.z + o.w * at.w;
#pragma unroll
      for (int m = 8; m; m >>= 1) {
        ps += __shfl_xor(ps, m);
        pt += __shfl_xor(pt, m);
      }
      if (tx == 0) {
        const size_t node = brow + rowl;
        ssrc0[node * 8 + head] = ps;
        stgt0[node * 8 + head] = pt;
      }
    }
    // stage W1 slice rows [head*64, head*64+64)
    for (int i = t; i < 1024; i += 256) {
      const int k = i >> 4, c4 = (i & 15) * 4;
      *(float4*)&W1s[k][c4] =
          *(const float4*)&W1[(size_t)(head * 64 + k) * 64 + c4];
    }
    __syncthreads();
    float acc2[2][4] = {};
#pragma unroll 4
    for (int k = 0; k < 64; ++k) {
      const float4 w4 = *(const float4*)&W1s[k][tx * 4];
      const float a0 = tile[ty * 2 + 0][k];
      const float a1 = tile[ty * 2 + 1][k];
      acc2[0][0] = fmaf(a0, w4.x, acc2[0][0]);
      acc2[0][1] = fmaf(a0, w4.y, acc2[0][1]);
      acc2[0][2] = fmaf(a0, w4.z, acc2[0][2]);
      acc2[0][3] = fmaf(a0, w4.w, acc2[0][3]);
      acc2[1][0] = fmaf(a1, w4.x, acc2[1][0]);
      acc2[1][1] = fmaf(a1, w4.y, acc2[1][1]);
      acc2[1][2] = fmaf(a1, w4.z, acc2[1][2]);
      acc2[1][3] = fmaf(a1, w4.w, acc2[1][3]);
    }
    // Ph layout [m][8 heads][64]
#pragma unroll
    for (int r = 0; r < 2; ++r) {
      float4 o;
      o.x = acc2[r][0]; o.y = acc2[r][1]; o.z = acc2[r][2]; o.w = acc2[r][3];
      *(float4*)&Ph[(size_t)(brow + ty * 2 + r) * 512 + head * 64 + tx * 4] = o;
    }
  }
}

// ---------------------------------------------------------------------------
// D2: layer-0 attention via Ph, FEATURE-quarter XCD split. Block b: xcd=b&7,
// fs=(b&7)>>1 (16-feature slice), n=((b>>3)<<1)|(b&1)  [bijective].
// Per-XCD Ph footprint = 4096*8heads*64B = 2MB (L2-resident). Each block
// computes the FULL 8-head sum for its slice -> writes proj1 slice (+b1)
// directly: no part buffer, no finalize dispatch.
// Lane layout: eg=lane>>4 (4-way edges); l16: hA=l16>>2 (head 0..3, pairs
// with hA+4), f4i=l16&3 (float4 within slice). Two accumulators = ILP-2.
// ---------------------------------------------------------------------------
__global__ __launch_bounds__(64) void attnF_kernel(
    const float* __restrict__ Ph, const float* __restrict__ ssrc0,
    const float* __restrict__ stgt0, const int* __restrict__ deg,
    const unsigned short* __restrict__ cols, const float* __restrict__ b1,
    float* __restrict__ proj1) {
  const int b = blockIdx.x;
  const int xg = b & 7;
  const int fs = xg >> 1;               // feature-quarter 0..3
  const int n = ((b >> 3) << 1) | (xg & 1);
  const int lane = threadIdx.x;         // 64 threads = 1 wave
  __shared__ int sm_[CAP];              // 512 B
  __shared__ float sw[CAP * 9];         // 4.6 KB, stride 9 (coprime 32)
  const int d = deg[n];
  for (int i = lane; i < d; i += 64) sm_[i] = cols[(size_t)n * CAP + i];
  __syncthreads();
  // per-edge scores, all 8 heads (one contiguous 32B stgt0 load per edge)
  const float4 ssA = *(const float4*)&ssrc0[n * 8];
  const float4 ssB = *(const float4*)&ssrc0[n * 8 + 4];
  for (int i = lane; i < d; i += 64) {
    const int m = sm_[i];
    const float4 t0 = *(const float4*)&stgt0[m * 8];
    const float4 t1 = *(const float4*)&stgt0[m * 8 + 4];
    float s0 = ssA.x + t0.x, s1 = ssA.y + t0.y, s2 = ssA.z + t0.z,
          s3 = ssA.w + t0.w;
    float s4 = ssB.x + t1.x, s5 = ssB.y + t1.y, s6 = ssB.z + t1.z,
          s7 = ssB.w + t1.w;
    sw[i * 9 + 0] = s0 >= 0.f ? s0 : 0.2f * s0;
    sw[i * 9 + 1] = s1 >= 0.f ? s1 : 0.2f * s1;
    sw[i * 9 + 2] = s2 >= 0.f ? s2 : 0.2f * s2;
    sw[i * 9 + 3] = s3 >= 0.f ? s3 : 0.2f * s3;
    sw[i * 9 + 4] = s4 >= 0.f ? s4 : 0.2f * s4;
    sw[i * 9 + 5] = s5 >= 0.f ? s5 : 0.2f * s5;
    sw[i * 9 + 6] = s6 >= 0.f ? s6 : 0.2f * s6;
    sw[i * 9 + 7] = s7 >= 0.f ? s7 : 0.2f * s7;
  }
  __syncthreads();
  // softmax per head; keep only the two sinv values this lane needs
  // (compile-time select avoids runtime-indexed array -> no scratch, rule#20)
  const int eg = lane >> 4;
  const int l16 = lane & 15;
  const int hA = l16 >> 2, f4i = l16 & 3;
  float sA = 0.f, sB = 0.f;
#pragma unroll
  for (int h = 0; h < 8; ++h) {
    float mx = -1e30f;
    for (int e = lane; e < d; e += 64) mx = fmaxf(mx, sw[e * 9 + h]);
#pragma unroll
    for (int o = 32; o; o >>= 1) mx = fmaxf(mx, __shfl_xor(mx, o));
    float sum = 0.f;
    for (int e = lane; e < d; e += 64) {
      float w = __expf(sw[e * 9 + h] - mx);
      sw[e * 9 + h] = w;
      sum += w;
    }
#pragma unroll
    for (int o = 32; o; o >>= 1) sum += __shfl_xor(sum, o);
    const float inv = 1.0f / sum;
    if (h == hA) sA = inv;
    if (h == hA + 4) sB = inv;
  }
  __syncthreads();
  // gather: per edge, lane loads Ph[m][hA*64 + fs*16 + f4i*4] (head hA) and
  // the same for head hA+4; accumulate separately (per-head normalization).
  const int offA = hA * 64 + fs * 16 + f4i * 4;
  const int offB = offA + 256;  // (hA+4)*64
  float4 a0 = make_float4(0.f, 0.f, 0.f, 0.f), a1 = a0;
  for (int e = eg; e < d; e += 4) {
    const int m = sm_[e];
    const float wA = sw[e * 9 + hA];
    const float wB = sw[e * 9 + hA + 4];
    const float4 pA = *(const float4*)&Ph[(size_t)m * 512 + offA];
    const float4 pB = *(const float4*)&Ph[(size_t)m * 512 + offB];
    a0.x = fmaf(wA, pA.x, a0.x); a0.y = fmaf(wA, pA.y, a0.y);
    a0.z = fmaf(wA, pA.z, a0.z); a0.w = fmaf(wA, pA.w, a0.w);
    a1.x = fmaf(wB, pB.x, a1.x); a1.y = fmaf(wB, pB.y, a1.y);
    a1.z = fmaf(wB, pB.z, a1.z); a1.w = fmaf(wB, pB.w, a1.w);
  }
  float4 acc;
  acc.x = a0.x * sA + a1.x * sB;
  acc.y = a0.y * sA + a1.y * sB;
  acc.z = a0.z * sA + a1.z * sB;
  acc.w = a0.w * sA + a1.w * sB;
  // reduce over hA (xor 4,8) then eg (xor 16,32); f4i preserved
#pragma unroll
  for (int o = 4; o <= 32; o <<= 1) {
    acc.x += __shfl_xor(acc.x, o);
    acc.y += __shfl_xor(acc.y, o);
    acc.z += __shfl_xor(acc.z, o);
    acc.w += __shfl_xor(acc.w, o);
  }
  if (lane < 4) {  // lane == f4i, eg==0, hA==0
    const float4 bb = *(const float4*)&b1[fs * 16 + lane * 4];
    float4 o;
    o.x = acc.x + bb.x; o.y = acc.y + bb.y;
    o.z = acc.z + bb.z; o.w = acc.w + bb.w;
    *(float4*)&proj1[(size_t)n * 64 + fs * 16 + lane * 4] = o;
  }
}

// ---------------------------------------------------------------------------
// D3: attn layer 1 fused with on-the-fly scores1. Per node: compute own
// ssrc1 from proj1[n]; per edge load proj1[m] ONCE -> LDS stash + a_tgt1 dot
// (4-step intra-group shuffle) -> score; softmax; weighted sum from stash.
// STASH=80 rows (max deg ~42+self, z~6 margin); LDS ~21KB -> 7 blocks/CU.
// ---------------------------------------------------------------------------
__global__ __launch_bounds__(64) void attn1f_kernel(
    const float* __restrict__ proj1, const float* __restrict__ a_src1,
    const float* __restrict__ a_tgt1, const int* __restrict__ deg,
    const unsigned short* __restrict__ cols, float* __restrict__ out) {
  const int n = blockIdx.x;
  const int lane = threadIdx.x;  // 64 threads = 1 wave
  __shared__ int sm_[CAP];          // 512 B
  __shared__ float4 rows[STASH * 16];  // 20 KB: rows[e*16+f4]
  __shared__ float sw[STASH];
  const int dfull = deg[n];
  const int d = dfull < STASH ? dfull : STASH;
  for (int i = lane; i < d; i += 64) sm_[i] = cols[(size_t)n * CAP + i];
  __syncthreads();
  // own ssrc1 = dot(proj1[n], a_src1)  (proj1 already includes b1)
  float ps = proj1[(size_t)n * 64 + lane] * a_src1[lane];
#pragma unroll
  for (int o = 32; o; o >>= 1) ps += __shfl_xor(ps, o);
  const float ssn = ps;
  // edges: stash proj1[m] rows + on-the-fly stgt1 dot -> leaky score
  const int eg = lane >> 4, f4 = lane & 15;
  const float4 at4 = *(const float4*)&a_tgt1[f4 * 4];
  for (int e = eg; e < d; e += 4) {
    const int m = sm_[e];
    const float4 pv = *(const float4*)&proj1[(size_t)m * 64 + f4 * 4];
    rows[e * 16 + f4] = pv;
    float pt = pv.x * at4.x + pv.y * at4.y + pv.z * at4.z + pv.w * at4.w;
#pragma unroll
    for (int o = 1; o <= 8; o <<= 1) pt += __shfl_xor(pt, o);  // 16-lane group
    if (f4 == 0) {
      float s = ssn + pt;
      sw[e] = s >= 0.f ? s : 0.2f * s;
    }
  }
  __syncthreads();
  // softmax over d edges (single wave)
  float mx = -1e30f;
  for (int e = lane; e < d; e += 64) mx = fmaxf(mx, sw[e]);
#pragma unroll
  for (int o = 32; o; o >>= 1) mx = fmaxf(mx, __shfl_xor(mx, o));
  float sum = 0.f;
  for (int e = lane; e < d; e += 64) {
    float w = __expf(sw[e] - mx);
    sw[e] = w;
    sum += w;
  }
#pragma unroll
  for (int o = 32; o; o >>= 1) sum += __shfl_xor(sum, o);
  const float sinv = 1.0f / sum;
  __syncthreads();
  // weighted sum from the LDS stash (no second gather)
  float4 acc = make_float4(0.f, 0.f, 0.f, 0.f);
  for (int e = eg; e < d; e += 4) {
    const float w = sw[e];
    const float4 pv = rows[e * 16 + f4];
    acc.x = fmaf(w, pv.x, acc.x);
    acc.y = fmaf(w, pv.y, acc.y);
    acc.z = fmaf(w, pv.z, acc.z);
    acc.w = fmaf(w, pv.w, acc.w);
  }
#pragma unroll
  for (int o = 16; o <= 32; o <<= 1) {
    acc.x += __shfl_xor(acc.x, o);
    acc.y += __shfl_xor(acc.y, o);
    acc.z += __shfl_xor(acc.z, o);
    acc.w += __shfl_xor(acc.w, o);
  }
  if (lane < 16) {  // lane == f4, eg == 0
    acc.x *= sinv; acc.y *= sinv; acc.z *= sinv; acc.w *= sinv;
    *(float4*)&out[(size_t)n * 64 + lane * 4] = acc;
  }
}

// ---------------------------------------------------------------------------
extern "C" void kernel_launch(void* const* d_in, const int* in_sizes, int n_in,
                              void* d_out, int out_size, void* d_ws, size_t ws_size,
                              hipStream_t stream) {
  const float* x      = (const float*)d_in[0];
  const float* mask   = (const float*)d_in[1];
  const float* W0     = (const float*)d_in[2];
  const float* b0     = (const float*)d_in[3];
  const float* a_src0 = (const float*)d_in[4];
  const float* a_tgt0 = (const float*)d_in[5];
  const float* W1     = (const float*)d_in[6];
  const float* b1     = (const float*)d_in[7];
  const float* a_src1 = (const float*)d_in[8];
  const float* a_tgt1 = (const float*)d_in[9];
  float* out = (float*)d_out;

  // workspace layout (~10.6 MB)
  float* ws    = (float*)d_ws;
  float* Ph    = ws;                          // 4096*512 (8 MB)
  float* proj1 = Ph + NNODES * 512;           // 4096*64 (1 MB)
  float* ssrc0 = proj1 + NNODES * 64;         // 4096*8
  float* stgt0 = ssrc0 + NNODES * 8;          // 4096*8
  int* deg = (int*)(stgt0 + NNODES * 8);      // 4096
  unsigned short* cols = (unsigned short*)(deg + NNODES);  // 4096*CAP u16 (1MB)

  // D1: gemm0+scores0+Ph (first 1024 blocks) + edge extraction (4096 blocks)
  phase1_kernel<<<NNODES + 1024, 256, 0, stream>>>(
      mask, deg, cols, x, W0, b0, a_src0, a_tgt0, W1, Ph, ssrc0, stgt0);
  // D2: layer-0 attention -> proj1 slices (feature-quarter XCD split)
  attnF_kernel<<<NNODES * 4, 64, 0, stream>>>(Ph, ssrc0, stgt0, deg, cols,
                                              b1, proj1);
  // D3: attn layer 1 with fused on-the-fly scores1
  attn1f_kernel<<<NNODES, 64, 0, stream>>>(proj1, a_src1, a_tgt1, deg, cols,
                                           out);
}

// Round 23
// 56.729 us; speedup vs baseline: 1.4833x; 1.4833x over previous
//
#include <hip/hip_runtime.h>
#include <hip/hip_bf16.h>

#define NNODES 4096
#define CAP 128

// Ledger: R11 grid.sync ~100us. R13 per-node W1 536MB. R15 node-amortize
// stall. R16 head-half XCD (69.4). R17 Ph linearity (64.3). R18 u16 cols +
// folded sinv + ILP2 (59.5). R19/R21 head-quarter XCD, 1-wave attnQ (56.8).
// R20 2-wave -> regression (58.2). R22 feature-quarter -> 4x redundant
// softmax, 84.1 regression. R23: revert to R21 exactly (best proven).

// ---------------------------------------------------------------------------
// Phase 1: blocks [0,1024) = gemm0 tiles (+scores0 +Ph mini-GEMM), issued
// first to overlap under the mask scan; blocks [1024,5120) = edge rows.
// ---------------------------------------------------------------------------
__global__ __launch_bounds__(256) void phase1_kernel(
    const float* __restrict__ mask, int* __restrict__ deg,
    unsigned short* __restrict__ cols, const float* __restrict__ x,
    const float* __restrict__ W0, const float* __restrict__ b0,
    const float* __restrict__ a_src0, const float* __restrict__ a_tgt0,
    const float* __restrict__ W1, float* __restrict__ Ph,
    float* __restrict__ ssrc0, float* __restrict__ stgt0) {
  __shared__ float smem[6144];  // 24 KB
  const int t = threadIdx.x;
  if (blockIdx.x >= 1024) {
    const int n = blockIdx.x - 1024;
    const int lane = t & 63, wid = t >> 6;
    int* wsum = (int*)smem;
    const float4* row = (const float4*)(mask + (size_t)n * NNODES);
    float4 v[4];
    int cnt = 0;
#pragma unroll
    for (int j = 0; j < 4; ++j) {
      v[j] = row[t + 256 * j];  // coalesced
      cnt += (v[j].x == 0.0f) + (v[j].y == 0.0f) + (v[j].z == 0.0f) +
             (v[j].w == 0.0f);
    }
    int xs = cnt;
#pragma unroll
    for (int o = 1; o < 64; o <<= 1) {
      int y = __shfl_up(xs, o);
      if (lane >= o) xs += y;
    }
    if (lane == 63) wsum[wid] = xs;
    __syncthreads();
    int base = 0;
    for (int w = 0; w < wid; ++w) base += wsum[w];
    int off = base + xs - cnt;
    if (t == 0) {
      int total = wsum[0] + wsum[1] + wsum[2] + wsum[3];
      deg[n] = total < CAP ? total : CAP;
    }
    unsigned short* dst = cols + (size_t)n * CAP;
#pragma unroll
    for (int j = 0; j < 4; ++j) {
      const int c0 = (t + 256 * j) * 4;
      float fv[4] = {v[j].x, v[j].y, v[j].z, v[j].w};
#pragma unroll
      for (int k = 0; k < 4; ++k) {
        if (fv[k] == 0.0f) {
          if (off < CAP) dst[off] = (unsigned short)(c0 + k);
          ++off;
        }
      }
    }
  } else {
    // gemm0: 32x64 tile, K=128, BK=32 chunks, 2x4 reg blocking
    float(*As)[36] = (float(*)[36])smem;            // [0,1152)
    float(*Ws)[64] = (float(*)[64])(smem + 1152);   // [1152,3200)
    const int bx = blockIdx.x;
    const int brow = (bx & 127) * 32;
    const int head = bx >> 7;
    const int bcol = head * 64;
    const int tx = t & 15, ty = t >> 4;
    const int ar = t >> 3, ak = (t & 7) * 4;
    float acc[2][4] = {};
    for (int c = 0; c < 4; ++c) {
      const int k0 = c * 32;
      *(float4*)&As[ar][ak] =
          *(const float4*)&x[(size_t)(brow + ar) * 128 + k0 + ak];
#pragma unroll
      for (int q = 0; q < 2; ++q) {
        int i = t + q * 256;
        int k = i >> 4, c4 = (i & 15) * 4;
        *(float4*)&Ws[k][c4] =
            *(const float4*)&W0[(size_t)(k0 + k) * 512 + bcol + c4];
      }
      __syncthreads();
#pragma unroll 2
      for (int kk = 0; kk < 32; kk += 4) {
        float4 a0 = *(const float4*)&As[ty * 2 + 0][kk];
        float4 a1 = *(const float4*)&As[ty * 2 + 1][kk];
#pragma unroll
        for (int j = 0; j < 4; ++j) {
          float4 w = *(const float4*)&Ws[kk + j][tx * 4];
          float av0 = ((const float*)&a0)[j];
          float av1 = ((const float*)&a1)[j];
          acc[0][0] = fmaf(av0, w.x, acc[0][0]);
          acc[0][1] = fmaf(av0, w.y, acc[0][1]);
          acc[0][2] = fmaf(av0, w.z, acc[0][2]);
          acc[0][3] = fmaf(av0, w.w, acc[0][3]);
          acc[1][0] = fmaf(av1, w.x, acc[1][0]);
          acc[1][1] = fmaf(av1, w.y, acc[1][1]);
          acc[1][2] = fmaf(av1, w.z, acc[1][2]);
          acc[1][3] = fmaf(av1, w.w, acc[1][3]);
        }
      }
      __syncthreads();
    }
    // proj0 tile (+bias) -> LDS; fused scores0. Then Ph = tile @ W1slice.
    float(*tile)[64] = (float(*)[64])smem;          // [0,2048)
    float(*W1s)[64] = (float(*)[64])(smem + 2048);  // [2048,6144)
    const float4 bv = *(const float4*)&b0[bcol + tx * 4];
    const float4 as = *(const float4*)&a_src0[head * 64 + tx * 4];
    const float4 at = *(const float4*)&a_tgt0[head * 64 + tx * 4];
#pragma unroll
    for (int r = 0; r < 2; ++r) {
      float4 o;
      o.x = acc[r][0] + bv.x; o.y = acc[r][1] + bv.y;
      o.z = acc[r][2] + bv.z; o.w = acc[r][3] + bv.w;
      const int rowl = ty * 2 + r;
      *(float4*)&tile[rowl][tx * 4] = o;
      float ps = o.x * as.x + o.y * as.y + o.z * as.z + o.w * as.w;
      float pt = o.x * at.x + o.y * at.y + o.z * at.z + o.w * at.w;
#pragma unroll
      for (int m = 8; m; m >>= 1) {
        ps += __shfl_xor(ps, m);
        pt += __shfl_xor(pt, m);
      }
      if (tx == 0) {
        const size_t node = brow + rowl;
        ssrc0[node * 8 + head] = ps;
        stgt0[node * 8 + head] = pt;
      }
    }
    // stage W1 slice rows [head*64, head*64+64)
    for (int i = t; i < 1024; i += 256) {
      const int k = i >> 4, c4 = (i & 15) * 4;
      *(float4*)&W1s[k][c4] =
          *(const float4*)&W1[(size_t)(head * 64 + k) * 64 + c4];
    }
    __syncthreads();
    float acc2[2][4] = {};
#pragma unroll 4
    for (int k = 0; k < 64; ++k) {
      const float4 w4 = *(const float4*)&W1s[k][tx * 4];
      const float a0 = tile[ty * 2 + 0][k];
      const float a1 = tile[ty * 2 + 1][k];
      acc2[0][0] = fmaf(a0, w4.x, acc2[0][0]);
      acc2[0][1] = fmaf(a0, w4.y, acc2[0][1]);
      acc2[0][2] = fmaf(a0, w4.z, acc2[0][2]);
      acc2[0][3] = fmaf(a0, w4.w, acc2[0][3]);
      acc2[1][0] = fmaf(a1, w4.x, acc2[1][0]);
      acc2[1][1] = fmaf(a1, w4.y, acc2[1][1]);
      acc2[1][2] = fmaf(a1, w4.z, acc2[1][2]);
      acc2[1][3] = fmaf(a1, w4.w, acc2[1][3]);
    }
    // Ph layout [m][8 heads][64]
#pragma unroll
    for (int r = 0; r < 2; ++r) {
      float4 o;
      o.x = acc2[r][0]; o.y = acc2[r][1]; o.z = acc2[r][2]; o.w = acc2[r][3];
      *(float4*)&Ph[(size_t)(brow + ty * 2 + r) * 512 + head * 64 + tx * 4] = o;
    }
  }
}

// ---------------------------------------------------------------------------
// D2: layer-0 attention via Ph, head-QUARTER XCD split (R19-proven 1-wave).
// Block b: xcd=b&7, fq=(b&7)>>1 (quarter: 2 heads), n=((b>>3)<<1)|(b&1).
// One wave: lanes = (grp=lane>>5) x (hl=(lane&31)>>4) x (f4=lane&15).
// ---------------------------------------------------------------------------
__global__ __launch_bounds__(64) void attnQ_kernel(
    const float* __restrict__ Ph, const float* __restrict__ ssrc0,
    const float* __restrict__ stgt0, const int* __restrict__ deg,
    const unsigned short* __restrict__ cols, float* __restrict__ part) {
  const int b = blockIdx.x;
  const int xg = b & 7;
  const int fq = xg >> 1;               // head-quarter 0..3
  const int n = ((b >> 3) << 1) | (xg & 1);
  const int lane = threadIdx.x;         // 64 threads = 1 wave
  __shared__ int sm_[CAP];              // 512 B
  __shared__ float sw[CAP * 3];         // 1.5 KB, stride 3 (coprime 32)
  const int d = deg[n];
  for (int i = lane; i < d; i += 64) sm_[i] = cols[(size_t)n * CAP + i];
  __syncthreads();
  const int hbase = fq * 2;
  const float ss0 = ssrc0[n * 8 + hbase + 0];
  const float ss1 = ssrc0[n * 8 + hbase + 1];
  for (int i = lane; i < d * 2; i += 64) {
    const int e = i >> 1, h = i & 1;
    float s = (h ? ss1 : ss0) + stgt0[sm_[e] * 8 + hbase + h];
    sw[e * 3 + h] = s >= 0.f ? s : 0.2f * s;
  }
  __syncthreads();
  float sinv[2];
#pragma unroll
  for (int h = 0; h < 2; ++h) {  // single wave owns both heads (no race)
    float mx = -1e30f;
    for (int e = lane; e < d; e += 64) mx = fmaxf(mx, sw[e * 3 + h]);
#pragma unroll
    for (int o = 32; o; o >>= 1) mx = fmaxf(mx, __shfl_xor(mx, o));
    float sum = 0.f;
    for (int e = lane; e < d; e += 64) {
      float w = __expf(sw[e * 3 + h] - mx);
      sw[e * 3 + h] = w;
      sum += w;
    }
#pragma unroll
    for (int o = 32; o; o >>= 1) sum += __shfl_xor(sum, o);
    sinv[h] = 1.0f / sum;  // full butterfly: all lanes hold it
  }
  __syncthreads();
  // gather: 512B per edge (2 heads x 64f), 2-way edge split + ILP-2
  const int grp = lane >> 5;
  const int l32 = lane & 31;
  const int hl = l32 >> 4;
  const float s = sinv[hl];
  float4 a0 = make_float4(0.f, 0.f, 0.f, 0.f), a1 = a0;
  int e = grp;
  for (; e + 2 < d; e += 4) {
    const int m0 = sm_[e], m1 = sm_[e + 2];
    const float w0 = sw[e * 3 + hl], w1 = sw[(e + 2) * 3 + hl];
    const float4 p0 =
        *(const float4*)&Ph[(size_t)m0 * 512 + fq * 128 + l32 * 4];
    const float4 p1 =
        *(const float4*)&Ph[(size_t)m1 * 512 + fq * 128 + l32 * 4];
    a0.x = fmaf(w0, p0.x, a0.x); a0.y = fmaf(w0, p0.y, a0.y);
    a0.z = fmaf(w0, p0.z, a0.z); a0.w = fmaf(w0, p0.w, a0.w);
    a1.x = fmaf(w1, p1.x, a1.x); a1.y = fmaf(w1, p1.y, a1.y);
    a1.z = fmaf(w1, p1.z, a1.z); a1.w = fmaf(w1, p1.w, a1.w);
  }
  for (; e < d; e += 2) {
    const float w = sw[e * 3 + hl];
    const float4 pv =
        *(const float4*)&Ph[(size_t)sm_[e] * 512 + fq * 128 + l32 * 4];
    a0.x = fmaf(w, pv.x, a0.x); a0.y = fmaf(w, pv.y, a0.y);
    a0.z = fmaf(w, pv.z, a0.z); a0.w = fmaf(w, pv.w, a0.w);
  }
  float4 acc;
  acc.x = (a0.x + a1.x) * s;
  acc.y = (a0.y + a1.y) * s;
  acc.z = (a0.z + a1.z) * s;
  acc.w = (a0.w + a1.w) * s;
  // reduce across hl (xor16) then grp (xor32)
#pragma unroll
  for (int o = 16; o <= 32; o <<= 1) {
    acc.x += __shfl_xor(acc.x, o);
    acc.y += __shfl_xor(acc.y, o);
    acc.z += __shfl_xor(acc.z, o);
    acc.w += __shfl_xor(acc.w, o);
  }
  if (lane < 16) {
    *(float4*)&part[(size_t)fq * (NNODES * 64) + (size_t)n * 64 + lane * 4] =
        acc;
  }
}

// ---------------------------------------------------------------------------
// D3: proj1 = part0+part1+part2+part3 + b1; fused scores1 (16-lane reduce).
// ---------------------------------------------------------------------------
__global__ __launch_bounds__(256) void finalize_scores1_kernel(
    const float* __restrict__ part, const float* __restrict__ bias,
    const float* __restrict__ a_src1, const float* __restrict__ a_tgt1,
    float* __restrict__ proj1, float* __restrict__ ssrc1,
    float* __restrict__ stgt1) {
  const int i = blockIdx.x * 256 + threadIdx.x;  // float4 idx, 65536 total
  const float4* p = (const float4*)part;
  float4 a = p[i], b = p[i + 65536], c = p[i + 131072], dd = p[i + 196608];
  const int f4 = i & 15;
  const float4 bb = *(const float4*)&bias[f4 * 4];
  float4 r;
  r.x = a.x + b.x + c.x + dd.x + bb.x;
  r.y = a.y + b.y + c.y + dd.y + bb.y;
  r.z = a.z + b.z + c.z + dd.z + bb.z;
  r.w = a.w + b.w + c.w + dd.w + bb.w;
  ((float4*)proj1)[i] = r;
  const float4 as = *(const float4*)&a_src1[f4 * 4];
  const float4 at = *(const float4*)&a_tgt1[f4 * 4];
  float ps = r.x * as.x + r.y * as.y + r.z * as.z + r.w * as.w;
  float pt = r.x * at.x + r.y * at.y + r.z * at.z + r.w * at.w;
#pragma unroll
  for (int m = 8; m; m >>= 1) {
    ps += __shfl_xor(ps, m);
    pt += __shfl_xor(pt, m);
  }
  if (f4 == 0) {
    const int node = i >> 4;
    ssrc1[node] = ps;
    stgt1[node] = pt;
  }
}

// ---------------------------------------------------------------------------
// D4: attn layer 1 (H=1): one wave per node; float4 gather, 4-way edge split.
// ---------------------------------------------------------------------------
__global__ void attn1_kernel(
    const float* __restrict__ proj, const float* __restrict__ s_src,
    const float* __restrict__ s_tgt, const int* __restrict__ deg,
    const unsigned short* __restrict__ cols, float* __restrict__ out) {
  const int n = blockIdx.x;
  const int tid = threadIdx.x;  // 64 threads = 1 wave
  __shared__ int sm_[CAP];
  __shared__ float sw[CAP];
  const int d = deg[n];
  for (int i = tid; i < d; i += 64) sm_[i] = cols[(size_t)n * CAP + i];
  __syncthreads();
  const float ssn = s_src[n];
  for (int i = tid; i < d; i += 64) {
    float s = ssn + s_tgt[sm_[i]];
    sw[i] = s >= 0.f ? s : 0.2f * s;
  }
  __syncthreads();
  float mx = -1e30f;
  for (int e = tid; e < d; e += 64) mx = fmaxf(mx, sw[e]);
#pragma unroll
  for (int o = 32; o; o >>= 1) mx = fmaxf(mx, __shfl_xor(mx, o));
  float sum = 0.f;
  for (int e = tid; e < d; e += 64) {
    float w = __expf(sw[e] - mx);
    sw[e] = w;
    sum += w;
  }
#pragma unroll
  for (int o = 32; o; o >>= 1) sum += __shfl_xor(sum, o);
  const float sinv = 1.0f / sum;
  __syncthreads();
  const int f4 = tid & 15, grp = tid >> 4;  // 16 float4 outputs, 4-way edges
  float4 acc = make_float4(0.f, 0.f, 0.f, 0.f);
  for (int e = grp; e < d; e += 4) {
    const float w = sw[e];
    const float4 pv = *(const float4*)&proj[(size_t)sm_[e] * 64 + f4 * 4];
    acc.x = fmaf(w, pv.x, acc.x);
    acc.y = fmaf(w, pv.y, acc.y);
    acc.z = fmaf(w, pv.z, acc.z);
    acc.w = fmaf(w, pv.w, acc.w);
  }
#pragma unroll
  for (int o = 16; o <= 32; o <<= 1) {
    acc.x += __shfl_xor(acc.x, o);
    acc.y += __shfl_xor(acc.y, o);
    acc.z += __shfl_xor(acc.z, o);
    acc.w += __shfl_xor(acc.w, o);
  }
  if (grp == 0) {
    acc.x *= sinv; acc.y *= sinv; acc.z *= sinv; acc.w *= sinv;
    *(float4*)&out[(size_t)n * 64 + f4 * 4] = acc;
  }
}

// ---------------------------------------------------------------------------
extern "C" void kernel_launch(void* const* d_in, const int* in_sizes, int n_in,
                              void* d_out, int out_size, void* d_ws, size_t ws_size,
                              hipStream_t stream) {
  const float* x      = (const float*)d_in[0];
  const float* mask   = (const float*)d_in[1];
  const float* W0     = (const float*)d_in[2];
  const float* b0     = (const float*)d_in[3];
  const float* a_src0 = (const float*)d_in[4];
  const float* a_tgt0 = (const float*)d_in[5];
  const float* W1     = (const float*)d_in[6];
  const float* b1     = (const float*)d_in[7];
  const float* a_src1 = (const float*)d_in[8];
  const float* a_tgt1 = (const float*)d_in[9];
  float* out = (float*)d_out;

  // workspace layout (~15.6 MB)
  float* ws    = (float*)d_ws;
  float* Ph    = ws;                          // 4096*512 (8 MB)
  float* part  = Ph + NNODES * 512;           // 4*4096*64 (4 MB)
  float* proj1 = part + 4 * NNODES * 64;      // 4096*64
  float* ssrc0 = proj1 + NNODES * 64;         // 4096*8
  float* stgt0 = ssrc0 + NNODES * 8;          // 4096*8
  float* ssrc1 = stgt0 + NNODES * 8;          // 4096
  float* stgt1 = ssrc1 + NNODES;              // 4096
  int* deg = (int*)(stgt1 + NNODES);          // 4096
  unsigned short* cols = (unsigned short*)(deg + NNODES);  // 4096*CAP u16 (1MB)

  // D1: gemm0+scores0+Ph (first 1024 blocks) + edge extraction (4096 blocks)
  phase1_kernel<<<NNODES + 1024, 256, 0, stream>>>(
      mask, deg, cols, x, W0, b0, a_src0, a_tgt0, W1, Ph, ssrc0, stgt0);
  // D2: layer-0 attention -> part quarters (head-quarter XCD split, 1 wave)
  attnQ_kernel<<<NNODES * 4, 64, 0, stream>>>(Ph, ssrc0, stgt0, deg, cols, part);
  // D3: proj1 = sum(part) + b1, scores1
  finalize_scores1_kernel<<<256, 256, 0, stream>>>(part, b1, a_src1, a_tgt1,
                                                   proj1, ssrc1, stgt1);
  // D4: attn layer 1
  attn1_kernel<<<NNODES, 64, 0, stream>>>(proj1, ssrc1, stgt1, deg, cols, out);
}